// Round 8
// baseline (237.495 us; speedup 1.0000x reference)
//
#include <hip/hip_runtime.h>
#include <cmath>

// Problem geometry (fixed by the reference): 128 images of 512x512 f32.
static constexpr int IMH = 512;
static constexpr int IMW = 512;
static constexpr int IMG_PIX = IMH * IMW;

struct Weights {
    float kx[7];
    float ky[13];
};

__global__ void init_minmax_kernel(int* __restrict__ mm, int nimg) {
    int i = blockIdx.x * blockDim.x + threadIdx.x;
    if (i < nimg) {
        mm[2 * i]     = 0x7f7fffff;  // +FLT_MAX bits (min accumulator)
        mm[2 * i + 1] = 0;           // 0.0f bits (max accumulator; blur > 0)
    }
}

// Column-sweep fused kernel: zero LDS, zero barriers, zero bank conflicts.
// Wave = 64 lanes <-> 64 columns (56 outputs + halo). 8 waves per block sweep
// 8 independent 70/76-row chunks (64 output rows each) -> 32 waves/CU.
// Per row: grad via register history + 2 bpermutes (precomputed addrs),
// blurX via 6 bpermutes (reflect folded into the address table), blurY via a
// 13-register ring with static indexing. FP contraction disabled by pragma
// (bit-exact mul-then-add, same order as the reference) -- no asm barriers,
// full scheduling freedom.
__global__ __launch_bounds__(512) void blur_kernel(
        const float* __restrict__ in, float* __restrict__ blur,
        int* __restrict__ mm, Weights wt) {
#pragma clang fp contract(off)
    const int band = blockIdx.x;              // 0..9
    const int img  = blockIdx.y;              // 0..127
    const int k    = threadIdx.x >> 6;        // row chunk 0..7
    const int lane = threadIdx.x & 63;
    const int cb   = band * 56 - 4;           // wave covers cols cb..cb+63
    const int c    = cb + lane;
    const int c_ld = min(max(c, 0), IMW - 1); // clamped load col (dead lanes)
    const bool cvalid = (lane >= 4) && (lane <= 59) && (c <= IMW - 1);
    const bool has_l  = (c >= 1);
    const bool has_r  = (c <= IMW - 2);

    const float* __restrict__ ip = in + (size_t)img * IMG_PIX;
    float* __restrict__ bp = blur + (size_t)img * IMG_PIX;

    // Precomputed ds_bpermute byte addresses.
    const int a_lm1 = ((lane + 63) & 63) << 2;
    const int a_lp1 = ((lane + 1) & 63) << 2;
    int sb0, sb1, sb2, sb4, sb5, sb6;
    {
        int t;
        t = c - 3; t = t < 0 ? -t : (t > IMW - 1 ? 2 * (IMW - 1) - t : t); sb0 = ((t - cb) & 63) << 2;
        t = c - 2; t = t < 0 ? -t : (t > IMW - 1 ? 2 * (IMW - 1) - t : t); sb1 = ((t - cb) & 63) << 2;
        t = c - 1; t = t < 0 ? -t : (t > IMW - 1 ? 2 * (IMW - 1) - t : t); sb2 = ((t - cb) & 63) << 2;
        t = c + 1; t = t < 0 ? -t : (t > IMW - 1 ? 2 * (IMW - 1) - t : t); sb4 = ((t - cb) & 63) << 2;
        t = c + 2; t = t < 0 ? -t : (t > IMW - 1 ? 2 * (IMW - 1) - t : t); sb5 = ((t - cb) & 63) << 2;
        t = c + 3; t = t < 0 ? -t : (t > IMW - 1 ? 2 * (IMW - 1) - t : t); sb6 = ((t - cb) & 63) << 2;
    }

    // Chunk k: output rows 64k..64k+63; sweep rows gr0..gr0+R-1.
    const int gr0    = (k == 0) ? 0 : 64 * k - 6;
    const int tail_n = (k == 0 || k == 7) ? 5 : 11;   // R-65, R=70 or 76

    // x register pipeline: rows gr-1, gr, gr+1 (+1 prefetch), moving pointers
    const float* xp = ip + (size_t)gr0 * IMW + c_ld;
    float x_prev = (k == 0) ? 0.0f : xp[-IMW];
    float x_cur  = xp[0];
    float x_next = xp[IMW];
    const float* xp_pref = xp + 2 * (size_t)IMW;
    float* op = bp + (size_t)(gr0 + 6) * IMW + c;     // first regular orow

    float w[13];                                       // bx ring, static idx
    float tmn = 3.402823466e38f;
    float tmx = 0.0f;

#define GM_ROW(S, DO_OUT, DN, PREF)                                            \
    {                                                                          \
        float x_pref = (PREF);                                                 \
        int xi_ = __float_as_int(x_cur);                                       \
        float xl_ = __int_as_float(__builtin_amdgcn_ds_bpermute(a_lm1, xi_));  \
        float xr_ = __int_as_float(__builtin_amdgcn_ds_bpermute(a_lp1, xi_));  \
        float lf_ = has_l ? xl_ : 0.0f;                                        \
        float rt_ = has_r ? xr_ : 0.0f;                                        \
        float gv_ = (DN) - x_prev;                                             \
        float gh_ = rt_ - lf_;                                                 \
        float sg_ = gv_ * gv_ + gh_ * gh_;   /* contract(off): mul,mul,add */  \
        sg_ = sg_ + 1e-6f;                                                     \
        float g_ = sqrtf(sg_);                                                 \
        int gi_ = __float_as_int(g_);                                          \
        float b0_ = __int_as_float(__builtin_amdgcn_ds_bpermute(sb0, gi_));    \
        float b1_ = __int_as_float(__builtin_amdgcn_ds_bpermute(sb1, gi_));    \
        float b2_ = __int_as_float(__builtin_amdgcn_ds_bpermute(sb2, gi_));    \
        float b4_ = __int_as_float(__builtin_amdgcn_ds_bpermute(sb4, gi_));    \
        float b5_ = __int_as_float(__builtin_amdgcn_ds_bpermute(sb5, gi_));    \
        float b6_ = __int_as_float(__builtin_amdgcn_ds_bpermute(sb6, gi_));    \
        float ax_ = 0.0f;                                                      \
        ax_ += wt.kx[0] * b0_;                                                 \
        ax_ += wt.kx[1] * b1_;                                                 \
        ax_ += wt.kx[2] * b2_;                                                 \
        ax_ += wt.kx[3] * g_;                                                  \
        ax_ += wt.kx[4] * b4_;                                                 \
        ax_ += wt.kx[5] * b5_;                                                 \
        ax_ += wt.kx[6] * b6_;                                                 \
        w[(S) % 13] = ax_;                                                     \
        if (DO_OUT) {                                                          \
            float ay_ = 0.0f;                                                  \
            ay_ += wt.ky[0]  * w[((S) + 1)  % 13];                             \
            ay_ += wt.ky[1]  * w[((S) + 2)  % 13];                             \
            ay_ += wt.ky[2]  * w[((S) + 3)  % 13];                             \
            ay_ += wt.ky[3]  * w[((S) + 4)  % 13];                             \
            ay_ += wt.ky[4]  * w[((S) + 5)  % 13];                             \
            ay_ += wt.ky[5]  * w[((S) + 6)  % 13];                             \
            ay_ += wt.ky[6]  * w[((S) + 7)  % 13];                             \
            ay_ += wt.ky[7]  * w[((S) + 8)  % 13];                             \
            ay_ += wt.ky[8]  * w[((S) + 9)  % 13];                             \
            ay_ += wt.ky[9]  * w[((S) + 10) % 13];                             \
            ay_ += wt.ky[10] * w[((S) + 11) % 13];                             \
            ay_ += wt.ky[11] * w[((S) + 12) % 13];                             \
            ay_ += wt.ky[12] * w[((S) + 13) % 13];                             \
            if (cvalid) {                                                      \
                *op = ay_;                                                     \
                tmn = fminf(tmn, ay_);                                         \
                tmx = fmaxf(tmx, ay_);                                         \
            }                                                                  \
            op += IMW;                                                         \
        }                                                                      \
        x_prev = x_cur; x_cur = x_next; x_next = x_pref;                       \
        xp_pref += IMW;                                                        \
    }

    // ---- peel: ring fill, rows gr0..gr0+12 (one output at s=12) ----
    GM_ROW(0,  false, x_next, xp_pref[0])
    GM_ROW(1,  false, x_next, xp_pref[0])
    GM_ROW(2,  false, x_next, xp_pref[0])
    GM_ROW(3,  false, x_next, xp_pref[0])
    GM_ROW(4,  false, x_next, xp_pref[0])
    GM_ROW(5,  false, x_next, xp_pref[0])
    GM_ROW(6,  false, x_next, xp_pref[0])
    GM_ROW(7,  false, x_next, xp_pref[0])
    GM_ROW(8,  false, x_next, xp_pref[0])
    GM_ROW(9,  false, x_next, xp_pref[0])
    GM_ROW(10, false, x_next, xp_pref[0])
    GM_ROW(11, false, x_next, xp_pref[0])
    GM_ROW(12, true,  x_next, xp_pref[0])

    // ---- top reflected outputs (k==0: rows 0..5 from ring rows 0..11) ----
    if (k == 0) {
        #pragma unroll
        for (int orow = 0; orow < 6; ++orow) {
            float ay = 0.0f;
            #pragma unroll
            for (int j = 0; j < 13; ++j) {
                int t = orow + j - 6;
                t = t < 0 ? -t : t;              // compile-time per (orow,j)
                ay += wt.ky[j] * w[t];           // slot == row for k==0
            }
            if (cvalid) {
                bp[(size_t)orow * IMW + c] = ay;
                tmn = fminf(tmn, ay);
                tmx = fmaxf(tmx, ay);
            }
        }
    }

    // ---- main loop: rows gr0+13 .. gr0+64, fully guard-free ----
    for (int giter = 1; giter <= 4; ++giter) {
        GM_ROW(0,  true, x_next, xp_pref[0])
        GM_ROW(1,  true, x_next, xp_pref[0])
        GM_ROW(2,  true, x_next, xp_pref[0])
        GM_ROW(3,  true, x_next, xp_pref[0])
        GM_ROW(4,  true, x_next, xp_pref[0])
        GM_ROW(5,  true, x_next, xp_pref[0])
        GM_ROW(6,  true, x_next, xp_pref[0])
        GM_ROW(7,  true, x_next, xp_pref[0])
        GM_ROW(8,  true, x_next, xp_pref[0])
        GM_ROW(9,  true, x_next, xp_pref[0])
        GM_ROW(10, true, x_next, xp_pref[0])
        GM_ROW(11, true, x_next, xp_pref[0])
        GM_ROW(12, true, x_next, xp_pref[0])
    }

    // ---- tail: rows gr0+65 .. gr0+R-1 (5 or 11 rows), guarded ----
    // slot (65+S)%13 == S; row 511 (k==7, S==4) takes dn=0; prefetch guarded.
#define GM_TAILROW(S)                                                          \
    if ((S) < tail_n) {                                                        \
        GM_ROW(S, true,                                                        \
               ((gr0 + 65 + (S)) == IMH - 1) ? 0.0f : x_next,                  \
               ((gr0 + 67 + (S)) <= IMH - 1) ? xp_pref[0] : 0.0f)              \
    }
    GM_TAILROW(0)
    GM_TAILROW(1)
    GM_TAILROW(2)
    GM_TAILROW(3)
    GM_TAILROW(4)
    GM_TAILROW(5)
    GM_TAILROW(6)
    GM_TAILROW(7)
    GM_TAILROW(8)
    GM_TAILROW(9)
    GM_TAILROW(10)
#undef GM_TAILROW
#undef GM_ROW

    // ---- bottom reflected outputs (k==7: rows 506..511) ----
    // Row t (500..511) sits at slot (t-442)%13 after the 70-row sweep.
    if (k == 7) {
        #pragma unroll
        for (int oo = 0; oo < 6; ++oo) {
            int orow = 506 + oo;
            float ay = 0.0f;
            #pragma unroll
            for (int j = 0; j < 13; ++j) {
                int t = orow + j - 6;
                t = t > IMH - 1 ? 2 * (IMH - 1) - t : t;  // compile-time
                ay += wt.ky[j] * w[(t - 442) % 13];
            }
            if (cvalid) {
                bp[(size_t)orow * IMW + c] = ay;
                tmn = fminf(tmn, ay);
                tmx = fmaxf(tmx, ay);
            }
        }
    }

    // ---- per-wave reduce + per-image atomics ----
    #pragma unroll
    for (int off = 32; off > 0; off >>= 1) {
        tmn = fminf(tmn, __shfl_xor(tmn, off));
        tmx = fmaxf(tmx, __shfl_xor(tmx, off));
    }
    if (lane == 0) {
        // blur values strictly positive -> float order == int order
        atomicMin(&mm[2 * img], __float_as_int(tmn));
        atomicMax(&mm[2 * img + 1], __float_as_int(tmx));
    }
}

// Normalize + emit both masks as INT32 0/1 (bool output dtype -> int32).
// blurNe holds blur f32 bit patterns on entry (second half of d_out used as
// scratch); each thread overwrites exactly the elements it read.
__global__ __launch_bounds__(256) void mask_kernel(
        const int* __restrict__ mm, int* __restrict__ edge,
        int* __restrict__ blurNe, long long n4) {
#pragma clang fp contract(off)
    const long long stride = (long long)gridDim.x * blockDim.x;
    for (long long i = (long long)blockIdx.x * blockDim.x + threadIdx.x;
         i < n4; i += stride) {
        int img = (int)(i >> 16);  // 262144/4 = 65536 vec4 per image
        float mn = __int_as_float(mm[2 * img]);
        float mx = __int_as_float(mm[2 * img + 1]);
        float d = mx - mn;
        int4 vi = reinterpret_cast<const int4*>(blurNe)[i];
        float4 v = make_float4(__int_as_float(vi.x), __int_as_float(vi.y),
                               __int_as_float(vi.z), __int_as_float(vi.w));
        // true division to match reference normalization exactly
        float n0 = (v.x - mn) / d;
        float n1 = (v.y - mn) / d;
        float n2 = (v.z - mn) / d;
        float n3 = (v.w - mn) / d;
        int4 e, ne;
        e.x = (n0 < 0.1f) ? 1 : 0;  ne.x = 1 - e.x;
        e.y = (n1 < 0.1f) ? 1 : 0;  ne.y = 1 - e.y;
        e.z = (n2 < 0.1f) ? 1 : 0;  ne.z = 1 - e.z;
        e.w = (n3 < 0.1f) ? 1 : 0;  ne.w = 1 - e.w;
        reinterpret_cast<int4*>(edge)[i] = e;
        reinterpret_cast<int4*>(blurNe)[i] = ne;
    }
}

extern "C" void kernel_launch(void* const* d_in, const int* in_sizes, int n_in,
                              void* d_out, int out_size, void* d_ws, size_t ws_size,
                              hipStream_t stream) {
    const float* x = (const float*)d_in[0];
    int* out = (int*)d_out;
    const long long N = (long long)in_sizes[0];        // 33554432
    const int nimg = (int)(N / IMG_PIX);               // 128
    float* blur = (float*)(out + N);                   // scratch in 2nd output half
    int* mm = (int*)d_ws;                              // 2 ints per image

    // f32 Gaussian weights, mimicking the jnp float32 ops
    Weights wt;
    {
        float tmp[13];
        float s = 0.0f;
        for (int i = 0; i < 7; ++i) {
            float t = (float)i - 3.0f;
            float u = t / 10.0f;
            tmp[i] = expf(-0.5f * (u * u));
            s += tmp[i];
        }
        for (int i = 0; i < 7; ++i) wt.kx[i] = tmp[i] / s;
        s = 0.0f;
        for (int i = 0; i < 13; ++i) {
            float t = (float)i - 6.0f;
            float u = t / 10.0f;
            tmp[i] = expf(-0.5f * (u * u));
            s += tmp[i];
        }
        for (int i = 0; i < 13; ++i) wt.ky[i] = tmp[i] / s;
    }

    init_minmax_kernel<<<1, 256, 0, stream>>>(mm, nimg);
    blur_kernel<<<dim3(10, nimg), 512, 0, stream>>>(x, blur, mm, wt);
    mask_kernel<<<2048, 256, 0, stream>>>(mm, out, (int*)blur, N / 4);
}